// Round 2
// baseline (816.836 us; speedup 1.0000x reference)
//
#include <hip/hip_runtime.h>
#include <math.h>

#define BB 2048   // batch
#define TT 128    // time steps
#define DD 512    // feature dim
#define NTASK (BB * TT)

// ---------------------------------------------------------------------------
// Kernel A: gi[g][t][b] = sum_d x[b,t,d] * w_ih[g,d]
// One wave per (b,t) task, 2 tasks in flight per loop iteration (4 outstanding
// dwordx4 loads). w_ih slices live in registers. Block 0 also zeroes d_out
// (replaces the hipMemsetAsync dispatch; gru's atomics need zeros).
// Output planes [gate][t*B + b] so kernel B reads coalesced.
// ---------------------------------------------------------------------------
__global__ __launch_bounds__(256) void gi_kernel(const float* __restrict__ x,
                                                 const float* __restrict__ w_ih,
                                                 float* __restrict__ gr,
                                                 float* __restrict__ gz,
                                                 float* __restrict__ gn,
                                                 float* __restrict__ out) {
    if (blockIdx.x == 0 && threadIdx.x < TT) out[threadIdx.x] = 0.0f;

    const int lane   = threadIdx.x & 63;
    const int wave   = blockIdx.x * (blockDim.x >> 6) + (threadIdx.x >> 6);
    const int nwaves = (gridDim.x * blockDim.x) >> 6;   // 8192

    const int doff = lane * 8;
    const float4 wr0 = *(const float4*)(w_ih + 0 * DD + doff);
    const float4 wr1 = *(const float4*)(w_ih + 0 * DD + doff + 4);
    const float4 wz0 = *(const float4*)(w_ih + 1 * DD + doff);
    const float4 wz1 = *(const float4*)(w_ih + 1 * DD + doff + 4);
    const float4 wn0 = *(const float4*)(w_ih + 2 * DD + doff);
    const float4 wn1 = *(const float4*)(w_ih + 2 * DD + doff + 4);

    // NTASK / nwaves == 32, even — process 2 tasks per iteration.
    for (int task = wave; task < NTASK; task += 2 * nwaves) {
        const int task2 = task + nwaves;
        const float* xp  = x + (size_t)task  * DD + doff;
        const float* xq  = x + (size_t)task2 * DD + doff;
        const float4 x0 = *(const float4*)(xp);
        const float4 x1 = *(const float4*)(xp + 4);
        const float4 y0 = *(const float4*)(xq);
        const float4 y1 = *(const float4*)(xq + 4);

        float sr = x0.x * wr0.x + x0.y * wr0.y + x0.z * wr0.z + x0.w * wr0.w +
                   x1.x * wr1.x + x1.y * wr1.y + x1.z * wr1.z + x1.w * wr1.w;
        float sz = x0.x * wz0.x + x0.y * wz0.y + x0.z * wz0.z + x0.w * wz0.w +
                   x1.x * wz1.x + x1.y * wz1.y + x1.z * wz1.z + x1.w * wz1.w;
        float sn = x0.x * wn0.x + x0.y * wn0.y + x0.z * wn0.z + x0.w * wn0.w +
                   x1.x * wn1.x + x1.y * wn1.y + x1.z * wn1.z + x1.w * wn1.w;
        float tr = y0.x * wr0.x + y0.y * wr0.y + y0.z * wr0.z + y0.w * wr0.w +
                   y1.x * wr1.x + y1.y * wr1.y + y1.z * wr1.z + y1.w * wr1.w;
        float tz = y0.x * wz0.x + y0.y * wz0.y + y0.z * wz0.z + y0.w * wz0.w +
                   y1.x * wz1.x + y1.y * wz1.y + y1.z * wz1.z + y1.w * wz1.w;
        float tn = y0.x * wn0.x + y0.y * wn0.y + y0.z * wn0.z + y0.w * wn0.w +
                   y1.x * wn1.x + y1.y * wn1.y + y1.z * wn1.z + y1.w * wn1.w;

        #pragma unroll
        for (int off = 32; off > 0; off >>= 1) {
            sr += __shfl_xor(sr, off);
            sz += __shfl_xor(sz, off);
            sn += __shfl_xor(sn, off);
            tr += __shfl_xor(tr, off);
            tz += __shfl_xor(tz, off);
            tn += __shfl_xor(tn, off);
        }

        if (lane == 0) {
            {
                const int b = task >> 7, t = task & (TT - 1);
                gr[t * BB + b] = sr;
                gz[t * BB + b] = sz;
                gn[t * BB + b] = sn;
            }
            {
                const int b = task2 >> 7, t = task2 & (TT - 1);
                gr[t * BB + b] = tr;
                gz[t * BB + b] = tz;
                gn[t * BB + b] = tn;
            }
        }
    }
}

// ---------------------------------------------------------------------------
// Kernel B: per-batch scalar GRU recurrence + batch-mean per t.
// 8 blocks x 256 threads (thread = batch element). Wave shuffle reduce ->
// LDS cross-wave reduce -> 1 atomicAdd per block per t.
// ---------------------------------------------------------------------------
__global__ __launch_bounds__(256) void gru_kernel(const float* __restrict__ gr,
                                                  const float* __restrict__ gz,
                                                  const float* __restrict__ gn,
                                                  const float* __restrict__ h0,
                                                  const float* __restrict__ w_hh,
                                                  const float* __restrict__ b_ih,
                                                  const float* __restrict__ b_hh,
                                                  float* __restrict__ out) {
    const int b    = blockIdx.x * 256 + threadIdx.x;
    const int lane = threadIdx.x & 63;
    const int wid  = threadIdx.x >> 6;          // 0..3
    __shared__ float red[4];

    const float whr = w_hh[0], whz = w_hh[1], whn = w_hh[2];
    const float br  = b_ih[0] + b_hh[0];
    const float bz  = b_ih[1] + b_hh[1];
    const float bn  = b_ih[2];
    const float bhn = b_hh[2];

    float h = h0[b];

    for (int t = 0; t < TT; ++t) {
        const float gir = gr[t * BB + b];
        const float giz = gz[t * BB + b];
        const float gin = gn[t * BB + b];

        const float ir  = gir + br + h * whr;
        const float iz  = giz + bz + h * whz;
        const float ghn = h * whn + bhn;

        const float r = 1.0f / (1.0f + expf(-ir));
        const float z = 1.0f / (1.0f + expf(-iz));
        const float n = tanhf(gin + bn + r * ghn);

        h = (1.0f - z) * n + z * h;

        float s = h;
        #pragma unroll
        for (int off = 32; off > 0; off >>= 1) s += __shfl_xor(s, off);
        if (lane == 0) red[wid] = s;
        __syncthreads();
        if (threadIdx.x == 0) {
            const float blk = red[0] + red[1] + red[2] + red[3];
            atomicAdd(out + t, blk * (1.0f / (float)BB));
        }
        __syncthreads();
    }
}

extern "C" void kernel_launch(void* const* d_in, const int* in_sizes, int n_in,
                              void* d_out, int out_size, void* d_ws, size_t ws_size,
                              hipStream_t stream) {
    const float* x    = (const float*)d_in[0];
    const float* h0   = (const float*)d_in[1];
    const float* w_ih = (const float*)d_in[2];
    const float* w_hh = (const float*)d_in[3];
    const float* b_ih = (const float*)d_in[4];
    const float* b_hh = (const float*)d_in[5];
    float* out = (float*)d_out;

    float* gr = (float*)d_ws;        // [TT][BB]
    float* gz = gr + NTASK;
    float* gn = gz + NTASK;

    // gi_kernel block 0 zeroes d_out (needed by gru's atomics); stream order
    // guarantees it lands before gru_kernel runs.
    gi_kernel<<<2048, 256, 0, stream>>>(x, w_ih, gr, gz, gn, out);
    gru_kernel<<<BB / 256, 256, 0, stream>>>(gr, gz, gn, h0, w_hh, b_ih, b_hh, out);
}

// Round 3
// 745.565 us; speedup vs baseline: 1.0956x; 1.0956x over previous
//
#include <hip/hip_runtime.h>
#include <math.h>

#define BB 2048   // batch
#define TT 128    // time steps
#define DD 512    // feature dim
#define BPB 4     // batch elements per block (one per wave)

// ---------------------------------------------------------------------------
// Fused kernel: each block owns BPB=4 batch elements end-to-end.
//   Phase 1: wave w computes gi[b][t][g] (g = r,z,n) for b = blk*4+w, all t.
//            Coalesced: wave reads x[b][t][·] as one 2 KB segment (lane*8
//            floats), weights live in registers, 6-step shuffle reduce,
//            2-t unroll => 4 outstanding dwordx4 loads per wave.
//            gi parked in LDS (bank-conflict-padded).
//   Phase 2: lanes 0..3 of wave 0 run the 4 scalar GRU recurrences (128
//            sequential steps each) from LDS; per-t h written to LDS.
//   Phase 3: threads 0..127 sum the 4 per-block h's for their t and issue
//            one atomicAdd per (block,t). d_out zeroed by memsetAsync first.
// 512 blocks x 256 threads = 2 blocks/CU, 8 waves/CU for latency hiding.
// ---------------------------------------------------------------------------
__global__ __launch_bounds__(256) void gru_fused(const float* __restrict__ x,
                                                 const float* __restrict__ w_ih,
                                                 const float* __restrict__ h0,
                                                 const float* __restrict__ w_hh,
                                                 const float* __restrict__ b_ih,
                                                 const float* __restrict__ b_hh,
                                                 float* __restrict__ out) {
    // gi_s: logical [BPB][TT][3], flat with per-batch stride 385 (= 384+1 pad
    // so the 4 recurrence lanes land in different banks).
    __shared__ float gi_s[BPB * (TT * 3 + 1)];
    __shared__ float hall[TT * BPB];          // [t][bl]

    const int lane = threadIdx.x & 63;
    const int wid  = threadIdx.x >> 6;        // 0..3 == batch-local index
    const int b    = blockIdx.x * BPB + wid;

    const int doff = lane * 8;
    const float4 wr0 = *(const float4*)(w_ih + 0 * DD + doff);
    const float4 wr1 = *(const float4*)(w_ih + 0 * DD + doff + 4);
    const float4 wz0 = *(const float4*)(w_ih + 1 * DD + doff);
    const float4 wz1 = *(const float4*)(w_ih + 1 * DD + doff + 4);
    const float4 wn0 = *(const float4*)(w_ih + 2 * DD + doff);
    const float4 wn1 = *(const float4*)(w_ih + 2 * DD + doff + 4);

    float* gw = gi_s + wid * (TT * 3 + 1);

    // ---- Phase 1: gi for this wave's batch element, 2 timesteps per iter ----
    for (int t = 0; t < TT; t += 2) {
        const float* xp = x + ((size_t)b * TT + t) * DD + doff;
        const float4 x0 = *(const float4*)(xp);
        const float4 x1 = *(const float4*)(xp + 4);
        const float4 y0 = *(const float4*)(xp + DD);
        const float4 y1 = *(const float4*)(xp + DD + 4);

        float sr = x0.x * wr0.x + x0.y * wr0.y + x0.z * wr0.z + x0.w * wr0.w +
                   x1.x * wr1.x + x1.y * wr1.y + x1.z * wr1.z + x1.w * wr1.w;
        float sz = x0.x * wz0.x + x0.y * wz0.y + x0.z * wz0.z + x0.w * wz0.w +
                   x1.x * wz1.x + x1.y * wz1.y + x1.z * wz1.z + x1.w * wz1.w;
        float sn = x0.x * wn0.x + x0.y * wn0.y + x0.z * wn0.z + x0.w * wn0.w +
                   x1.x * wn1.x + x1.y * wn1.y + x1.z * wn1.z + x1.w * wn1.w;
        float tr = y0.x * wr0.x + y0.y * wr0.y + y0.z * wr0.z + y0.w * wr0.w +
                   y1.x * wr1.x + y1.y * wr1.y + y1.z * wr1.z + y1.w * wr1.w;
        float tz = y0.x * wz0.x + y0.y * wz0.y + y0.z * wz0.z + y0.w * wz0.w +
                   y1.x * wz1.x + y1.y * wz1.y + y1.z * wz1.z + y1.w * wz1.w;
        float tn = y0.x * wn0.x + y0.y * wn0.y + y0.z * wn0.z + y0.w * wn0.w +
                   y1.x * wn1.x + y1.y * wn1.y + y1.z * wn1.z + y1.w * wn1.w;

        #pragma unroll
        for (int off = 32; off > 0; off >>= 1) {
            sr += __shfl_xor(sr, off);
            sz += __shfl_xor(sz, off);
            sn += __shfl_xor(sn, off);
            tr += __shfl_xor(tr, off);
            tz += __shfl_xor(tz, off);
            tn += __shfl_xor(tn, off);
        }

        if (lane == 0) {
            gw[(t    ) * 3 + 0] = sr;
            gw[(t    ) * 3 + 1] = sz;
            gw[(t    ) * 3 + 2] = sn;
            gw[(t + 1) * 3 + 0] = tr;
            gw[(t + 1) * 3 + 1] = tz;
            gw[(t + 1) * 3 + 2] = tn;
        }
    }
    __syncthreads();

    // ---- Phase 2: scalar recurrence, lanes 0..3 of wave 0 ----
    if (threadIdx.x < BPB) {
        const int bl = threadIdx.x;
        const float whr = w_hh[0], whz = w_hh[1], whn = w_hh[2];
        const float br  = b_ih[0] + b_hh[0];
        const float bz  = b_ih[1] + b_hh[1];
        const float bn  = b_ih[2];
        const float bhn = b_hh[2];
        const float* g  = gi_s + bl * (TT * 3 + 1);

        float h = h0[blockIdx.x * BPB + bl];
        for (int t = 0; t < TT; ++t) {
            const float ir  = g[t * 3 + 0] + br + h * whr;
            const float iz  = g[t * 3 + 1] + bz + h * whz;
            const float ghn = h * whn + bhn;
            const float r = 1.0f / (1.0f + expf(-ir));
            const float z = 1.0f / (1.0f + expf(-iz));
            const float n = tanhf(g[t * 3 + 2] + bn + r * ghn);
            h = (1.0f - z) * n + z * h;
            hall[t * BPB + bl] = h;
        }
    }
    __syncthreads();

    // ---- Phase 3: per-t partial sum, one atomic per (block, t) ----
    if (threadIdx.x < TT) {
        const float4 hv = *(const float4*)(hall + threadIdx.x * BPB);
        const float s = hv.x + hv.y + hv.z + hv.w;
        atomicAdd(out + threadIdx.x, s * (1.0f / (float)BB));
    }
}

extern "C" void kernel_launch(void* const* d_in, const int* in_sizes, int n_in,
                              void* d_out, int out_size, void* d_ws, size_t ws_size,
                              hipStream_t stream) {
    const float* x    = (const float*)d_in[0];
    const float* h0   = (const float*)d_in[1];
    const float* w_ih = (const float*)d_in[2];
    const float* w_hh = (const float*)d_in[3];
    const float* b_ih = (const float*)d_in[4];
    const float* b_hh = (const float*)d_in[5];
    float* out = (float*)d_out;

    // Atomic accumulation target must start at zero (d_out is poisoned 0xAA).
    hipMemsetAsync(d_out, 0, (size_t)out_size * sizeof(float), stream);

    gru_fused<<<BB / BPB, 256, 0, stream>>>(x, w_ih, h0, w_hh, b_ih, b_hh, out);
}